// Round 1
// 178.822 us; speedup vs baseline: 1.2142x; 1.2142x over previous
//
#include <hip/hip_runtime.h>

// Correlation layer, fully fused single-pass banded-MFMA kernel (gfx950).
// out[b, dy*9+dx, y, x] = sum_c f1[b,c,y,x] * f2[b,c,y+dy-4,x+dx-4]
//
// R10: fuse the two-pass (cvt_f2 + corr_mfma) design into ONE kernel.
// Rationale (rocprof R9): corr_mfma was L3-BW-bound — 786 MB of load issue
// (each w2 row re-read by 9 y-blocks x 2 jm tiles) against a 13.7 MB/XCD
// working set >> 4 MB L2, served from Infinity Cache at ~8.6 TB/s; MfmaUtil
// 4.4%, HBM 10%. Plus a serialized ~120us cvt pass + 42.5 MB workspace
// round-trip. Fix: block 8 y-rows x 16 out-px, stage f2 (16 rows x 32 cols,
// halos included) + f1 (8x16) per 32-ch chunk in LDS with in-block fp32->bf16
// conversion — the dy/jm reuse moves from L3 into LDS (69 TB/s). This is the
// verified corr_fallback staging/fragment/epilogue machinery re-blocked
// (YB=1,64px -> YB=8,16px). No workspace, no pass 1.
//
//  - 512 blocks (= 8 b x 8 yg x 8 xg) x 512 threads = 2 blocks/CU exactly.
//  - b = id&7 pins each batch to one XCD (same as R9) for L2 locality of
//    the halo re-reads.
//  - LDS 50 KB: f2s 16x32x20 uints (40 KB) + f1s 8x16x20 uints (10 KB).
//    PXS=20 keeps the 5-uint4 px stride -> 8 lanes per 4-bank group,
//    perfectly balanced b128 reads (fallback-proven layout).
//  - Each wave owns one y row, full 9 dy, 2 banded 16x16x32 MFMA tiles:
//    acc = 9x2 float4 = 72 VGPR.

namespace {
constexpr int B_ = 8, C_ = 256, H_ = 64, W_ = 128;
constexpr int SIDE = 9, ND = 81, PAD = 4;
constexpr int HW = H_ * W_;
constexpr int KC = 32;                    // channels per LDS chunk
constexpr int NCH = C_ / KC;              // 8 chunks
constexpr int YB = 8;                     // output rows per block
constexpr int RWS = YB + 2 * PAD;         // 16 staged f2 rows
constexpr int XB = 16;                    // output cols per block
constexpr int F2PX = 32;                  // staged f2 cols (XB + 16 band)
constexpr int PXS = KC / 2 + 4;           // 20: ch-pair stride (+4 pad)
constexpr int F2U = RWS * (F2PX / 4) * (KC / 2);  // 2048 staging units
constexpr int F1U = YB * (XB / 4) * (KC / 2);     // 512 staging units
}

typedef __attribute__((ext_vector_type(8))) short short8;
typedef __attribute__((ext_vector_type(4))) float float4v;

__device__ __forceinline__ unsigned bf16rne(float f) {
  unsigned u = __float_as_uint(f);
  return (u + 0x7fffu + ((u >> 16) & 1u)) >> 16;
}
__device__ __forceinline__ unsigned packbf2(float lo, float hi) {
  return bf16rne(lo) | (bf16rne(hi) << 16);
}

__global__ __launch_bounds__(512, 4)
void corr_fused(const float* __restrict__ f1, const float* __restrict__ f2,
                float* __restrict__ out) {
  __shared__ __align__(16) unsigned f2s[RWS * F2PX * PXS];  // 40 KB
  __shared__ __align__(16) unsigned f1s[YB * XB * PXS];     // 10 KB

  const int id = blockIdx.x;
  const int b = id & 7;                   // XCD pin
  const int k = id >> 3;                  // 0..63
  const int xg = k & 7;
  const int yg = k >> 3;
  const int x0 = xg * XB;
  const int y0 = yg * YB;

  const int t = threadIdx.x;
  const int lane = t & 63;
  const int w = t >> 6;                   // wave 0..7 -> y row y0+w
  const int v = lane & 15;                // fragment pixel index
  const int q = lane >> 4;                // k-quad / C-row-group

  float4v acc[SIDE][2];
#pragma unroll
  for (int i = 0; i < SIDE; ++i) {
    acc[i][0] = (float4v){0.f, 0.f, 0.f, 0.f};
    acc[i][1] = (float4v){0.f, 0.f, 0.f, 0.f};
  }

  const float* __restrict__ f1b = f1 + (size_t)b * C_ * HW;
  const float* __restrict__ f2b = f2 + (size_t)b * C_ * HW;

  for (int ch = 0; ch < NCH; ++ch) {
    const int c0 = ch * KC;
    if (ch) __syncthreads();

    // ---- stage f2 tile: 16 rows x 32 cols x 32 ch, bf16-pair packed ----
    // unit u: cp = u&15 (ch pair), pxq = (u>>4)&7 (col quad), r = u>>7 (row)
#pragma unroll
    for (int u0 = 0; u0 < F2U; u0 += 512) {
      const int u = u0 + t;
      const int cp = u & 15;
      const int t2 = u >> 4;
      const int pxq = t2 & 7;
      const int r = t2 >> 3;              // 0..15
      const int ygl = y0 - PAD + r;
      const int xb = x0 - PAD + pxq * 4;
      float4 va = make_float4(0.f, 0.f, 0.f, 0.f), vb = va;
      if (ygl >= 0 && ygl < H_ && xb >= 0 && xb <= W_ - 4) {
        const float* p = f2b + ((size_t)(c0 + 2 * cp) * H_ + ygl) * W_ + xb;
        va = *(const float4*)p;
        vb = *(const float4*)(p + HW);
      }
      unsigned* d = &f2s[(r * F2PX + pxq * 4) * PXS + cp];
      d[0 * PXS] = packbf2(va.x, vb.x);
      d[1 * PXS] = packbf2(va.y, vb.y);
      d[2 * PXS] = packbf2(va.z, vb.z);
      d[3 * PXS] = packbf2(va.w, vb.w);
    }
    // ---- stage f1 tile: 8 rows x 16 cols x 32 ch (always in-bounds) ----
    {
      const int cp = t & 15;
      const int t2 = t >> 4;
      const int pxq = t2 & 3;
      const int r = t2 >> 2;              // 0..7
      const float* p =
          f1b + ((size_t)(c0 + 2 * cp) * H_ + (y0 + r)) * W_ + x0 + pxq * 4;
      const float4 va = *(const float4*)p;
      const float4 vb = *(const float4*)(p + HW);
      unsigned* d = &f1s[(r * XB + pxq * 4) * PXS + cp];
      d[0 * PXS] = packbf2(va.x, vb.x);
      d[1 * PXS] = packbf2(va.y, vb.y);
      d[2 * PXS] = packbf2(va.z, vb.z);
      d[3 * PXS] = packbf2(va.w, vb.w);
    }
    __syncthreads();

    // ---- banded MFMA: one y row per wave, 9 dy x 2 tiles ----
    const short8 af = __builtin_bit_cast(
        short8, *(const uint4*)&f1s[(w * XB + v) * PXS + 4 * q]);
#pragma unroll
    for (int dy = 0; dy < SIDE; ++dy) {
      const unsigned* fp = &f2s[((w + dy) * F2PX + v) * PXS + 4 * q];
      const short8 b0 = __builtin_bit_cast(short8, *(const uint4*)fp);
      const short8 b1 =
          __builtin_bit_cast(short8, *(const uint4*)(fp + 16 * PXS));
      acc[dy][0] =
          __builtin_amdgcn_mfma_f32_16x16x32_bf16(af, b0, acc[dy][0], 0, 0, 0);
      acc[dy][1] =
          __builtin_amdgcn_mfma_f32_16x16x32_bf16(af, b1, acc[dy][1], 0, 0, 0);
    }
  }

  // Epilogue: C/D col n = v, row m = q*4+r. tile0: dx = v-m in [0,8];
  // tile1: dx = v-m+16 in [1,8]. Each output element written exactly once.
  const int y = y0 + w;
  float* outb = out + (size_t)b * ND * HW + (size_t)y * W_ + x0;
#pragma unroll
  for (int dy = 0; dy < SIDE; ++dy) {
#pragma unroll
    for (int r = 0; r < 4; ++r) {
      const int m = q * 4 + r;
      const int dx0 = v - m;
      if (dx0 >= 0 && dx0 <= 8)
        outb[(size_t)(dy * SIDE + dx0) * HW + m] = acc[dy][0][r];
      const int dx1 = v - m + 16;
      if (dx1 <= 8)
        outb[(size_t)(dy * SIDE + dx1) * HW + m] = acc[dy][1][r];
    }
  }
}

extern "C" void kernel_launch(void* const* d_in, const int* in_sizes, int n_in,
                              void* d_out, int out_size, void* d_ws,
                              size_t ws_size, hipStream_t stream) {
  (void)in_sizes; (void)n_in; (void)out_size; (void)d_ws; (void)ws_size;
  const float* f1 = (const float*)d_in[0];
  const float* f2 = (const float*)d_in[1];
  float* out = (float*)d_out;
  corr_fused<<<dim3(512), 512, 0, stream>>>(f1, f2, out);
}